// Round 4
// baseline (119.033 us; speedup 1.0000x reference)
//
#include <hip/hip_runtime.h>
#include <stdint.h>

constexpr int NN  = 50000;
constexpr int NE  = 800000;
constexpr int H   = 128;
constexpr int CAP = 48;   // bucket capacity; P(indeg>=48 | Poisson(16)) ~ e^-70, guarded anyway
constexpr int RB  = 8;    // rows per MLP block

typedef int vint4 __attribute__((ext_vector_type(4)));

__device__ __forceinline__ uint32_t f32key(float f) {
  uint32_t b = __float_as_uint(f);
  return (b & 0x80000000u) ? ~b : (b | 0x80000000u);
}

// K1: logits + self-loop election key init + cnt/nsl zeroing.
__global__ void k_logits(const float* __restrict__ x,
                         const float* __restrict__ Wle, const float* __restrict__ ble,
                         float* __restrict__ logits, unsigned long long* __restrict__ lkey,
                         int* __restrict__ cnt, int* __restrict__ nsl) {
  int gid  = blockIdx.x * blockDim.x + threadIdx.x;
  int wave = gid >> 6, lane = threadIdx.x & 63;
  if (gid == 0) *nsl = 0;
  if (wave >= NN) return;
  const float* xr = x + (size_t)wave * H;
  float v = xr[lane] * Wle[lane] + xr[lane + 64] * Wle[lane + 64];
  for (int off = 32; off > 0; off >>= 1) v += __shfl_xor(v, off, 64);
  if (lane == 0) {
    float lg = v + ble[0];
    logits[wave] = lg;
    lkey[wave] = ((unsigned long long)f32key(lg) << 32) | (unsigned long long)(uint32_t)wave;
    cnt[wave] = 0;
  }
}

// K2: leader election, 4 edges/thread; parallel independent gathers, register filter.
__global__ void k_elect(const int* __restrict__ esrc, const int* __restrict__ edst,
                        const float* __restrict__ logits, unsigned long long* __restrict__ lkey) {
  int t = blockIdx.x * blockDim.x + threadIdx.x;
  if (t >= NE / 4) return;
  vint4 s4 = ((const vint4*)esrc)[t];
  vint4 d4 = ((const vint4*)edst)[t];
  float lg[4];
  unsigned long long lv[4];
#pragma unroll
  for (int i = 0; i < 4; ++i) lg[i] = logits[s4[i]];
#pragma unroll
  for (int i = 0; i < 4; ++i) lv[i] = lkey[d4[i]];
#pragma unroll
  for (int i = 0; i < 4; ++i) {
    unsigned long long key =
        ((unsigned long long)f32key(lg[i]) << 32) | (unsigned long long)(uint32_t)s4[i];
    if (lv[i] < key) atomicMax(&lkey[d4[i]], key);  // stale read only underestimates -> safe
  }
}

// K3: build self-leader list + bucket passing edges by destination (4 edges/thread).
__global__ void k_place(const int* __restrict__ esrc, const int* __restrict__ edst,
                        const unsigned long long* __restrict__ lkey,
                        int* __restrict__ cnt, int* __restrict__ bucket,
                        int* __restrict__ slist, int* __restrict__ nsl) {
  int t = blockIdx.x * blockDim.x + threadIdx.x;
  if (t < NN) {
    if ((uint32_t)lkey[t] == (uint32_t)t) {
      int p = atomicAdd(nsl, 1);
      slist[p] = t;
    }
  }
  if (t >= NE / 4) return;
  vint4 s4 = ((const vint4*)esrc)[t];
  vint4 d4 = ((const vint4*)edst)[t];
  uint32_t w[4];
#pragma unroll
  for (int i = 0; i < 4; ++i) w[i] = (uint32_t)lkey[d4[i]];
#pragma unroll
  for (int i = 0; i < 4; ++i) {
    if (w[i] == (uint32_t)d4[i]) {  // dst is a self-leader: its report is read
      int slot = atomicAdd(&cnt[d4[i]], 1);
      if (slot < CAP) bucket[(size_t)d4[i] * CAP + slot] = s4[i];
    }
  }
}

// K4: per self-leader, atomic-free neighbor-sum -> nmean written into out row.
__global__ void __launch_bounds__(128) k_gather(
    const int* __restrict__ slist, const int* __restrict__ nsl,
    const int* __restrict__ cnt, const int* __restrict__ bucket,
    const float* __restrict__ x, float* __restrict__ out) {
  int b = blockIdx.x;
  if (b >= *nsl) return;
  int node = slist[b];
  int c = cnt[node];
  int cc = min(c, CAP);
  __shared__ int ss[CAP];
  int j = threadIdx.x;
  if (j < cc) ss[j] = bucket[(size_t)node * CAP + j];
  __syncthreads();
  // order-insensitive (double) accumulation; 2-way unroll for MLP
  double a0 = 0.0, a1 = 0.0;
  int e = 0;
  for (; e + 1 < cc; e += 2) {
    a0 += (double)x[(size_t)ss[e] * H + j];
    a1 += (double)x[(size_t)ss[e + 1] * H + j];
  }
  if (e < cc) a0 += (double)x[(size_t)ss[e] * H + j];
  float rc = 1.0f / (float)max(c, 1);
  out[(size_t)node * H + j] = (float)(a0 + a1) * rc;
}

// K5: MLP on self-leader rows, RB rows per block (amortize weight reads), in-place on out.
__global__ void __launch_bounds__(128) k_mlp8(
    const int* __restrict__ slist, const int* __restrict__ nsl,
    const float* __restrict__ W1, const float* __restrict__ b1,
    const float* __restrict__ W2, const float* __restrict__ b2,
    float* __restrict__ out) {
  int base = blockIdx.x * RB;
  int ns = *nsl;
  if (base >= ns) return;
  int v = min(RB, ns - base);
  __shared__ float sm[RB][H];
  __shared__ int nodes[RB];
  int j = threadIdx.x;
  if (j < RB) nodes[j] = (j < v) ? slist[base + j] : 0;
  __syncthreads();
#pragma unroll
  for (int r = 0; r < RB; ++r)
    if (r < v) sm[r][j] = out[(size_t)nodes[r] * H + j];
  __syncthreads();
  float acc[RB];
#pragma unroll
  for (int r = 0; r < RB; ++r) acc[r] = b1[j];
  for (int k = 0; k < H; ++k) {
    float w = W1[k * H + j];
#pragma unroll
    for (int r = 0; r < RB; ++r) acc[r] = fmaf(sm[r][k], w, acc[r]);
  }
  __syncthreads();
#pragma unroll
  for (int r = 0; r < RB; ++r)
    sm[r][j] = 0.5f * acc[r] * (1.0f + erff(acc[r] * 0.70710678118654752f));
  __syncthreads();
#pragma unroll
  for (int r = 0; r < RB; ++r) acc[r] = b2[j];
  for (int k = 0; k < H; ++k) {
    float w = W2[k * H + j];
#pragma unroll
    for (int r = 0; r < RB; ++r) acc[r] = fmaf(sm[r][k], w, acc[r]);
  }
#pragma unroll
  for (int r = 0; r < RB; ++r)
    if (r < v) out[(size_t)nodes[r] * H + j] = acc[r];
}

// K6: non-self-leader rows copy their leader's report (or zero).
__global__ void k_out(const unsigned long long* __restrict__ lkey,
                      float* __restrict__ out) {
  int g = blockIdx.x * blockDim.x + threadIdx.x;
  int i = g >> 5, q = g & 31;
  if (i >= NN) return;
  int L = (int)(uint32_t)lkey[i];
  if (L == i) return;  // self-leader rows already final
  float4 v = make_float4(0.f, 0.f, 0.f, 0.f);
  if ((uint32_t)lkey[L] == (uint32_t)L)
    v = *(const float4*)(out + (size_t)L * H + q * 4);
  *(float4*)(out + (size_t)i * H + q * 4) = v;
}

extern "C" void kernel_launch(void* const* d_in, const int* in_sizes, int n_in,
                              void* d_out, int out_size, void* d_ws, size_t ws_size,
                              hipStream_t stream) {
  (void)in_sizes; (void)n_in; (void)out_size; (void)ws_size;
  const float* x   = (const float*)d_in[0];
  const int* ei    = (const int*)d_in[1];   // [2][NE] int32
  const float* Wle = (const float*)d_in[2];
  const float* ble = (const float*)d_in[3];
  const float* W1  = (const float*)d_in[4];
  const float* b1  = (const float*)d_in[5];
  const float* W2  = (const float*)d_in[6];
  const float* b2  = (const float*)d_in[7];
  float* out       = (float*)d_out;

  char* ws = (char*)d_ws;
  unsigned long long* lkey = (unsigned long long*)ws;        // 400000 B
  float* logits = (float*)(ws + 400000);                     // 200000 B
  int*   cnt    = (int*)  (ws + 600000);                     // 200000 B
  int*   slist  = (int*)  (ws + 800000);                     // 200000 B
  int*   nsl    = (int*)  (ws + 1000000);                    // 256 B
  int*   bucket = (int*)  (ws + 1000256);                    // NN*CAP*4 = 9.6 MB

  const int* esrc = ei;
  const int* edst = ei + NE;

  k_logits<<<(NN * 64 + 255) / 256, 256, 0, stream>>>(x, Wle, ble, logits, lkey, cnt, nsl);
  k_elect<<<(NE / 4 + 255) / 256, 256, 0, stream>>>(esrc, edst, logits, lkey);
  {
    int thr = (NN > NE / 4) ? NN : NE / 4;
    k_place<<<(thr + 255) / 256, 256, 0, stream>>>(esrc, edst, lkey, cnt, bucket, slist, nsl);
  }
  k_gather<<<NN, 128, 0, stream>>>(slist, nsl, cnt, bucket, x, out);
  k_mlp8<<<(NN + RB - 1) / RB, 128, 0, stream>>>(slist, nsl, W1, b1, W2, b2, out);
  k_out<<<(NN * 32 + 255) / 256, 256, 0, stream>>>(lkey, out);
}

// Round 5
// 107.937 us; speedup vs baseline: 1.1028x; 1.1028x over previous
//
#include <hip/hip_runtime.h>
#include <stdint.h>

constexpr int NN  = 50000;
constexpr int NE  = 800000;
constexpr int H   = 128;
constexpr int CAP = 48;   // bucket capacity; P(indeg>=48 | Poisson(16)) ~ e^-70, guarded anyway
constexpr int RB  = 8;    // rows per MLP block

__device__ __forceinline__ uint32_t f32key(float f) {
  uint32_t b = __float_as_uint(f);
  return (b & 0x80000000u) ? ~b : (b | 0x80000000u);
}

// K1: logits + self-loop election key init + cnt/nsl zeroing.
__global__ void k_logits(const float* __restrict__ x,
                         const float* __restrict__ Wle, const float* __restrict__ ble,
                         float* __restrict__ logits, unsigned long long* __restrict__ lkey,
                         int* __restrict__ cnt, int* __restrict__ nsl) {
  int gid  = blockIdx.x * blockDim.x + threadIdx.x;
  int wave = gid >> 6, lane = threadIdx.x & 63;
  if (gid == 0) *nsl = 0;
  if (wave >= NN) return;
  const float* xr = x + (size_t)wave * H;
  float v = xr[lane] * Wle[lane] + xr[lane + 64] * Wle[lane + 64];
  for (int off = 32; off > 0; off >>= 1) v += __shfl_xor(v, off, 64);
  if (lane == 0) {
    float lg = v + ble[0];
    logits[wave] = lg;
    lkey[wave] = ((unsigned long long)f32key(lg) << 32) | (unsigned long long)(uint32_t)wave;
    cnt[wave] = 0;
  }
}

// K2: leader election, 1 edge/thread, fire-and-forget atomicMax (no filter gather:
// the atomic result is unused, so the wave never waits on lkey).
__global__ void k_elect(const int* __restrict__ esrc, const int* __restrict__ edst,
                        const float* __restrict__ logits, unsigned long long* __restrict__ lkey) {
  int e = blockIdx.x * blockDim.x + threadIdx.x;
  if (e >= NE) return;
  int s = __builtin_nontemporal_load(&esrc[e]);
  int d = __builtin_nontemporal_load(&edst[e]);
  unsigned long long key =
      ((unsigned long long)f32key(logits[s]) << 32) | (unsigned long long)(uint32_t)s;
  atomicMax(&lkey[d], key);
}

// K3: build self-leader list + bucket passing edges by destination (1 edge/thread).
// Filter via 4-byte leader-index gather (low word of lkey); load esrc lazily.
__global__ void k_place(const int* __restrict__ esrc, const int* __restrict__ edst,
                        const unsigned long long* __restrict__ lkey,
                        int* __restrict__ cnt, int* __restrict__ bucket,
                        int* __restrict__ slist, int* __restrict__ nsl) {
  const int* __restrict__ leader_lo = (const int*)lkey;  // leader[i] = leader_lo[2*i]
  int t = blockIdx.x * blockDim.x + threadIdx.x;
  if (t < NN) {
    if (leader_lo[2 * t] == t) {
      int p = atomicAdd(nsl, 1);
      slist[p] = t;
    }
  }
  if (t >= NE) return;
  int d = __builtin_nontemporal_load(&edst[t]);
  if (leader_lo[2 * d] != d) return;  // dst's report never read
  int s = esrc[t];                    // lazy: only ~6% of edges reach here
  int slot = atomicAdd(&cnt[d], 1);
  if (slot < CAP) bucket[(size_t)d * CAP + slot] = s;
}

// K4: per self-leader, atomic-free neighbor-sum -> nmean written into out row.
__global__ void __launch_bounds__(128) k_gather(
    const int* __restrict__ slist, const int* __restrict__ nsl,
    const int* __restrict__ cnt, const int* __restrict__ bucket,
    const float* __restrict__ x, float* __restrict__ out) {
  int b = blockIdx.x;
  if (b >= *nsl) return;
  int node = slist[b];
  int c = cnt[node];
  int cc = min(c, CAP);
  __shared__ int ss[CAP];
  int j = threadIdx.x;
  if (j < cc) ss[j] = bucket[(size_t)node * CAP + j];
  __syncthreads();
  // order-insensitive (double) accumulation; 2-way unroll for MLP (memory-level parallelism)
  double a0 = 0.0, a1 = 0.0;
  int e = 0;
  for (; e + 1 < cc; e += 2) {
    a0 += (double)x[(size_t)ss[e] * H + j];
    a1 += (double)x[(size_t)ss[e + 1] * H + j];
  }
  if (e < cc) a0 += (double)x[(size_t)ss[e] * H + j];
  float rc = 1.0f / (float)max(c, 1);
  out[(size_t)node * H + j] = (float)(a0 + a1) * rc;
}

// K5: MLP on self-leader rows, RB rows per block (amortize weight reads), in-place on out.
__global__ void __launch_bounds__(128) k_mlp8(
    const int* __restrict__ slist, const int* __restrict__ nsl,
    const float* __restrict__ W1, const float* __restrict__ b1,
    const float* __restrict__ W2, const float* __restrict__ b2,
    float* __restrict__ out) {
  int base = blockIdx.x * RB;
  int ns = *nsl;
  if (base >= ns) return;
  int v = min(RB, ns - base);
  __shared__ float sm[RB][H];
  __shared__ int nodes[RB];
  int j = threadIdx.x;
  if (j < RB) nodes[j] = (j < v) ? slist[base + j] : 0;
  __syncthreads();
#pragma unroll
  for (int r = 0; r < RB; ++r)
    if (r < v) sm[r][j] = out[(size_t)nodes[r] * H + j];
  __syncthreads();
  float acc[RB];
#pragma unroll
  for (int r = 0; r < RB; ++r) acc[r] = b1[j];
  for (int k = 0; k < H; ++k) {
    float w = W1[k * H + j];
#pragma unroll
    for (int r = 0; r < RB; ++r) acc[r] = fmaf(sm[r][k], w, acc[r]);
  }
  __syncthreads();
#pragma unroll
  for (int r = 0; r < RB; ++r)
    sm[r][j] = 0.5f * acc[r] * (1.0f + erff(acc[r] * 0.70710678118654752f));
  __syncthreads();
#pragma unroll
  for (int r = 0; r < RB; ++r) acc[r] = b2[j];
  for (int k = 0; k < H; ++k) {
    float w = W2[k * H + j];
#pragma unroll
    for (int r = 0; r < RB; ++r) acc[r] = fmaf(sm[r][k], w, acc[r]);
  }
#pragma unroll
  for (int r = 0; r < RB; ++r)
    if (r < v) out[(size_t)nodes[r] * H + j] = acc[r];
}

// K6: non-self-leader rows copy their leader's report (or zero).
__global__ void k_out(const unsigned long long* __restrict__ lkey,
                      float* __restrict__ out) {
  const int* __restrict__ leader_lo = (const int*)lkey;
  int g = blockIdx.x * blockDim.x + threadIdx.x;
  int i = g >> 5, q = g & 31;
  if (i >= NN) return;
  int L = leader_lo[2 * i];
  if (L == i) return;  // self-leader rows already final
  float4 v = make_float4(0.f, 0.f, 0.f, 0.f);
  if (leader_lo[2 * L] == L)
    v = *(const float4*)(out + (size_t)L * H + q * 4);
  *(float4*)(out + (size_t)i * H + q * 4) = v;
}

extern "C" void kernel_launch(void* const* d_in, const int* in_sizes, int n_in,
                              void* d_out, int out_size, void* d_ws, size_t ws_size,
                              hipStream_t stream) {
  (void)in_sizes; (void)n_in; (void)out_size; (void)ws_size;
  const float* x   = (const float*)d_in[0];
  const int* ei    = (const int*)d_in[1];   // [2][NE] int32
  const float* Wle = (const float*)d_in[2];
  const float* ble = (const float*)d_in[3];
  const float* W1  = (const float*)d_in[4];
  const float* b1  = (const float*)d_in[5];
  const float* W2  = (const float*)d_in[6];
  const float* b2  = (const float*)d_in[7];
  float* out       = (float*)d_out;

  char* ws = (char*)d_ws;
  unsigned long long* lkey = (unsigned long long*)ws;        // 400000 B
  float* logits = (float*)(ws + 400000);                     // 200000 B
  int*   cnt    = (int*)  (ws + 600000);                     // 200000 B
  int*   slist  = (int*)  (ws + 800000);                     // 200000 B
  int*   nsl    = (int*)  (ws + 1000000);                    // 256 B
  int*   bucket = (int*)  (ws + 1000256);                    // NN*CAP*4 = 9.6 MB

  const int* esrc = ei;
  const int* edst = ei + NE;

  k_logits<<<(NN * 64 + 255) / 256, 256, 0, stream>>>(x, Wle, ble, logits, lkey, cnt, nsl);
  k_elect<<<(NE + 255) / 256, 256, 0, stream>>>(esrc, edst, logits, lkey);
  k_place<<<(NE + 255) / 256, 256, 0, stream>>>(esrc, edst, lkey, cnt, bucket, slist, nsl);
  k_gather<<<NN, 128, 0, stream>>>(slist, nsl, cnt, bucket, x, out);
  k_mlp8<<<(NN + RB - 1) / RB, 128, 0, stream>>>(slist, nsl, W1, b1, W2, b2, out);
  k_out<<<(NN * 32 + 255) / 256, 256, 0, stream>>>(lkey, out);
}

// Round 6
// 99.731 us; speedup vs baseline: 1.1935x; 1.0823x over previous
//
#include <hip/hip_runtime.h>
#include <stdint.h>

constexpr int NN  = 50000;
constexpr int NE  = 800000;
constexpr int H   = 128;
constexpr int CAP = 48;   // bucket capacity; P(indeg>=48 | Poisson(16)) ~ e^-70, guarded anyway
constexpr int RB  = 8;    // leaders per report block

__device__ __forceinline__ uint32_t f32key(float f) {
  uint32_t b = __float_as_uint(f);
  return (b & 0x80000000u) ? ~b : (b | 0x80000000u);
}

// K1: logits + self-loop election key init + cnt/nsl zeroing.
__global__ void k_logits(const float* __restrict__ x,
                         const float* __restrict__ Wle, const float* __restrict__ ble,
                         float* __restrict__ logits, unsigned long long* __restrict__ lkey,
                         int* __restrict__ cnt, int* __restrict__ nsl) {
  int gid  = blockIdx.x * blockDim.x + threadIdx.x;
  int wave = gid >> 6, lane = threadIdx.x & 63;
  if (gid == 0) *nsl = 0;
  if (wave >= NN) return;
  const float* xr = x + (size_t)wave * H;
  float v = xr[lane] * Wle[lane] + xr[lane + 64] * Wle[lane + 64];
  for (int off = 32; off > 0; off >>= 1) v += __shfl_xor(v, off, 64);
  if (lane == 0) {
    float lg = v + ble[0];
    logits[wave] = lg;
    lkey[wave] = ((unsigned long long)f32key(lg) << 32) | (unsigned long long)(uint32_t)wave;
    cnt[wave] = 0;
  }
}

// K2: leader election, 1 edge/thread, fire-and-forget atomicMax.
__global__ void k_elect(const int* __restrict__ esrc, const int* __restrict__ edst,
                        const float* __restrict__ logits, unsigned long long* __restrict__ lkey) {
  int e = blockIdx.x * blockDim.x + threadIdx.x;
  if (e >= NE) return;
  int s = __builtin_nontemporal_load(&esrc[e]);
  int d = __builtin_nontemporal_load(&edst[e]);
  unsigned long long key =
      ((unsigned long long)f32key(logits[s]) << 32) | (unsigned long long)(uint32_t)s;
  atomicMax(&lkey[d], key);
}

// K3: self-leader list + bucket passing edges by destination (1 edge/thread).
__global__ void k_place(const int* __restrict__ esrc, const int* __restrict__ edst,
                        const unsigned long long* __restrict__ lkey,
                        int* __restrict__ cnt, int* __restrict__ bucket,
                        int* __restrict__ slist, int* __restrict__ nsl) {
  const int* __restrict__ leader_lo = (const int*)lkey;  // leader[i] = leader_lo[2*i]
  int t = blockIdx.x * blockDim.x + threadIdx.x;
  if (t < NN) {
    if (leader_lo[2 * t] == t) {
      int p = atomicAdd(nsl, 1);
      slist[p] = t;
    }
  }
  if (t >= NE) return;
  int d = __builtin_nontemporal_load(&edst[t]);
  if (leader_lo[2 * d] != d) return;  // dst's report never read
  int s = esrc[t];                    // lazy: only ~6% of edges reach here
  int slot = atomicAdd(&cnt[d], 1);
  if (slot < CAP) bucket[(size_t)d * CAP + slot] = s;
}

// K4: fused neighbor-mean + 2-layer MLP; RB leaders per 256-thread block.
// Gather: the two 128-thread halves each sum one row at a time (exact f64 acc).
// MLP: each thread owns 4 of the 8 rows at its column j.
__global__ void __launch_bounds__(256) k_report(
    const int* __restrict__ slist, const int* __restrict__ nsl,
    const int* __restrict__ cnt, const int* __restrict__ bucket,
    const float* __restrict__ x,
    const float* __restrict__ W1, const float* __restrict__ b1,
    const float* __restrict__ W2, const float* __restrict__ b2,
    float* __restrict__ out) {
  int base = blockIdx.x * RB;
  int ns = *nsl;
  if (base >= ns) return;
  int v = min(RB, ns - base);

  __shared__ float sm[RB][H];   // nmean, then reused as W1-input
  __shared__ float hm[RB][H];   // gelu(h)
  __shared__ int   ss[RB][CAP];
  __shared__ int   nodes[RB];
  __shared__ int   craw[RB];

  int tid = threadIdx.x;
  int j = tid & 127, half = tid >> 7;

  if (tid < RB) {
    int node = slist[base + min(tid, v - 1)];
    nodes[tid] = node;
    craw[tid] = cnt[node];
  }
  __syncthreads();
  // neighbor lists -> LDS (each half loads its parity rows)
  for (int r = half; r < v; r += 2) {
    int cc = min(craw[r], CAP);
    if (j < cc) ss[r][j] = bucket[(size_t)nodes[r] * CAP + j];
  }
  __syncthreads();
  // gather nmean (order-insensitive exact f64 accumulation)
  for (int rp = 0; rp < RB / 2; ++rp) {
    int r = 2 * rp + half;
    if (r >= v) break;
    int c = craw[r], cc = min(c, CAP);
    double a0 = 0.0, a1 = 0.0;
    int e = 0;
    for (; e + 1 < cc; e += 2) {
      a0 += (double)x[(size_t)ss[r][e] * H + j];
      a1 += (double)x[(size_t)ss[r][e + 1] * H + j];
    }
    if (e < cc) a0 += (double)x[(size_t)ss[r][e] * H + j];
    sm[r][j] = (float)(a0 + a1) * (1.0f / (float)max(c, 1));
  }
  __syncthreads();

  // layer 1: h = gelu(nmean @ W1 + b1)
  float acc[RB / 2];
#pragma unroll
  for (int rr = 0; rr < RB / 2; ++rr) acc[rr] = b1[j];
  for (int k = 0; k < H; ++k) {
    float w = W1[k * H + j];
#pragma unroll
    for (int rr = 0; rr < RB / 2; ++rr)
      acc[rr] = fmaf(sm[half * (RB / 2) + rr][k], w, acc[rr]);
  }
#pragma unroll
  for (int rr = 0; rr < RB / 2; ++rr)
    hm[half * (RB / 2) + rr][j] =
        0.5f * acc[rr] * (1.0f + erff(acc[rr] * 0.70710678118654752f));
  __syncthreads();

  // layer 2: report = h @ W2 + b2 -> write straight to out (NT store)
#pragma unroll
  for (int rr = 0; rr < RB / 2; ++rr) acc[rr] = b2[j];
  for (int k = 0; k < H; ++k) {
    float w = W2[k * H + j];
#pragma unroll
    for (int rr = 0; rr < RB / 2; ++rr)
      acc[rr] = fmaf(hm[half * (RB / 2) + rr][k], w, acc[rr]);
  }
#pragma unroll
  for (int rr = 0; rr < RB / 2; ++rr) {
    int r = half * (RB / 2) + rr;
    if (r < v)
      __builtin_nontemporal_store(acc[rr], &out[(size_t)nodes[r] * H + j]);
  }
}

// K5: non-self-leader rows copy their leader's report (or zero).
__global__ void k_out(const unsigned long long* __restrict__ lkey,
                      float* __restrict__ out) {
  const int* __restrict__ leader_lo = (const int*)lkey;
  int g = blockIdx.x * blockDim.x + threadIdx.x;
  int i = g >> 5, q = g & 31;
  if (i >= NN) return;
  int L = leader_lo[2 * i];
  if (L == i) return;  // self-leader rows already final
  float4 v = make_float4(0.f, 0.f, 0.f, 0.f);
  if (leader_lo[2 * L] == L)
    v = *(const float4*)(out + (size_t)L * H + q * 4);
  float* o = out + (size_t)i * H + q * 4;
  __builtin_nontemporal_store(v.x, o + 0);
  __builtin_nontemporal_store(v.y, o + 1);
  __builtin_nontemporal_store(v.z, o + 2);
  __builtin_nontemporal_store(v.w, o + 3);
}

extern "C" void kernel_launch(void* const* d_in, const int* in_sizes, int n_in,
                              void* d_out, int out_size, void* d_ws, size_t ws_size,
                              hipStream_t stream) {
  (void)in_sizes; (void)n_in; (void)out_size; (void)ws_size;
  const float* x   = (const float*)d_in[0];
  const int* ei    = (const int*)d_in[1];   // [2][NE] int32
  const float* Wle = (const float*)d_in[2];
  const float* ble = (const float*)d_in[3];
  const float* W1  = (const float*)d_in[4];
  const float* b1  = (const float*)d_in[5];
  const float* W2  = (const float*)d_in[6];
  const float* b2  = (const float*)d_in[7];
  float* out       = (float*)d_out;

  char* ws = (char*)d_ws;
  unsigned long long* lkey = (unsigned long long*)ws;        // 400000 B
  float* logits = (float*)(ws + 400000);                     // 200000 B
  int*   cnt    = (int*)  (ws + 600000);                     // 200000 B
  int*   slist  = (int*)  (ws + 800000);                     // 200000 B
  int*   nsl    = (int*)  (ws + 1000000);                    // 256 B
  int*   bucket = (int*)  (ws + 1000256);                    // NN*CAP*4 = 9.6 MB

  const int* esrc = ei;
  const int* edst = ei + NE;

  k_logits<<<(NN * 64 + 255) / 256, 256, 0, stream>>>(x, Wle, ble, logits, lkey, cnt, nsl);
  k_elect<<<(NE + 255) / 256, 256, 0, stream>>>(esrc, edst, logits, lkey);
  k_place<<<(NE + 255) / 256, 256, 0, stream>>>(esrc, edst, lkey, cnt, bucket, slist, nsl);
  k_report<<<(NN + RB - 1) / RB, 256, 0, stream>>>(slist, nsl, cnt, bucket, x,
                                                   W1, b1, W2, b2, out);
  k_out<<<(NN * 32 + 255) / 256, 256, 0, stream>>>(lkey, out);
}